// Round 7
// baseline (18.465 us; speedup 1.0000x reference)
//
#include <hip/hip_runtime.h>

typedef float f32x4 __attribute__((ext_vector_type(4)));

#define WAVES_PER_BLOCK 16
#define BLOCK (WAVES_PER_BLOCK * 64)

// Fused triplet miner, LDS-staged labels.
//  - Each 1024-thread block stages the ENTIRE label array (16384 x int32 =
//    64 KB, exactly) into LDS once, coalesced. 2 blocks/CU (128/160 KB).
//  - One wave per anchor mines from LDS: 512 labels/iter (2x int4 per lane),
//    2-deep register prefetch, ballot+ffs for first-match.
//  - Same wave then gathers its anchor/pos/neg embedding rows and writes
//    them with NON-TEMPORAL stores (write-once stream, keep L2 for emb).
__global__ void __launch_bounds__(BLOCK, 2) triplet_fused_kernel(
    const int* __restrict__ labels,
    const f32x4* __restrict__ emb,    // [N][D4]
    f32x4* __restrict__ out,          // [3][N][D4]
    float* __restrict__ valid_out,    // [N]
    int N, int D4) {

    __shared__ int4 slab4[4096];      // 64 KB = all N labels
    const int4* lab4 = (const int4*)labels;
    int nq = N >> 2;                  // int4 chunks (N % 4 == 0, nq <= 4096)

    for (int k = threadIdx.x; k < nq; k += BLOCK)
        slab4[k] = lab4[k];
    __syncthreads();

    int lane = threadIdx.x & 63;
    int wid  = threadIdx.x >> 6;
    int i    = blockIdx.x * WAVES_PER_BLOCK + wid;   // anchor
    if (i >= N) return;                              // no barriers after this

    const int* slab = (const int*)slab4;
    int my = slab[i];

    int kbase = (i + 1) >> 2;         // first chunk containing j > i
    int p = -1, ng = -1;

    // 2-deep prefetch of 2 chunk-groups per iteration (clamped addresses).
    int4 a0 = slab4[min(kbase +       lane, nq - 1)];
    int4 b0 = slab4[min(kbase +  64 + lane, nq - 1)];
    int4 a1 = slab4[min(kbase + 128 + lane, nq - 1)];
    int4 b1 = slab4[min(kbase + 192 + lane, nq - 1)];

    while (true) {
        int4 a2 = slab4[min(kbase + 256 + lane, nq - 1)];
        int4 b2 = slab4[min(kbase + 320 + lane, nq - 1)];

        unsigned msA = 0, mdA = 0, msB = 0, mdB = 0;
        int kqA = kbase + lane;
        int kqB = kbase + 64 + lane;
        if (kqA < nq) {
            int j0 = kqA << 2;
            if (j0 + 0 > i) { if (a0.x == my) msA |= 1u; else mdA |= 1u; }
            if (j0 + 1 > i) { if (a0.y == my) msA |= 2u; else mdA |= 2u; }
            if (j0 + 2 > i) { if (a0.z == my) msA |= 4u; else mdA |= 4u; }
            if (j0 + 3 > i) { if (a0.w == my) msA |= 8u; else mdA |= 8u; }
        }
        if (kqB < nq) {
            // j = kqB*4 > i always holds here (kqB >= kbase+64), no mask needed
            if (b0.x == my) msB |= 1u; else mdB |= 1u;
            if (b0.y == my) msB |= 2u; else mdB |= 2u;
            if (b0.z == my) msB |= 4u; else mdB |= 4u;
            if (b0.w == my) msB |= 8u; else mdB |= 8u;
        }

        unsigned long long bsA = __ballot(msA != 0);
        unsigned long long bdA = __ballot(mdA != 0);
        unsigned long long bsB = __ballot(msB != 0);
        unsigned long long bdB = __ballot(mdB != 0);

        if (p < 0) {
            if (bsA) {
                int ls = (int)__ffsll(bsA) - 1;
                unsigned m = __shfl(msA, ls);
                p = ((kbase + ls) << 2) + (__ffs(m) - 1);
            } else if (bsB) {
                int ls = (int)__ffsll(bsB) - 1;
                unsigned m = __shfl(msB, ls);
                p = ((kbase + 64 + ls) << 2) + (__ffs(m) - 1);
            }
        }
        if (ng < 0) {
            if (bdA) {
                int ls = (int)__ffsll(bdA) - 1;
                unsigned m = __shfl(mdA, ls);
                ng = ((kbase + ls) << 2) + (__ffs(m) - 1);
            } else if (bdB) {
                int ls = (int)__ffsll(bdB) - 1;
                unsigned m = __shfl(mdB, ls);
                ng = ((kbase + 64 + ls) << 2) + (__ffs(m) - 1);
            }
        }

        kbase += 128;
        if ((p >= 0 && ng >= 0) || kbase >= nq) break;
        a0 = a1; b0 = b1; a1 = a2; b1 = b2;
    }

    float v  = (p >= 0 && ng >= 0) ? 1.0f : 0.0f;
    int   ps = (p  >= 0) ? p  : 0;   // index irrelevant when invalid (row zeroed)
    int   ns = (ng >= 0) ? ng : 0;

    if (lane == 0) valid_out[i] = v;

    // Write 3 rows (512 B each). Pass 1: lanes 0-31 -> anchor row,
    // lanes 32-63 -> pos row. Pass 2: lanes 0-31 -> neg row.
    size_t ND4 = (size_t)N * D4;
    int t   = lane >> 5;
    int src = (t == 0) ? i : ps;
    int d4  = lane & 31;              // D4 == 32: one f32x4 per lane

    f32x4 e = emb[(size_t)src * D4 + d4];
    f32x4 r; r.x = e.x * v; r.y = e.y * v; r.z = e.z * v; r.w = e.w * v;
    __builtin_nontemporal_store(r, &out[(size_t)t * ND4 + (size_t)i * D4 + d4]);

    if (lane < 32) {
        f32x4 e2 = emb[(size_t)ns * D4 + d4];
        f32x4 r2; r2.x = e2.x * v; r2.y = e2.y * v; r2.z = e2.z * v; r2.w = e2.w * v;
        __builtin_nontemporal_store(r2, &out[2 * ND4 + (size_t)i * D4 + d4]);
    }
}

extern "C" void kernel_launch(void* const* d_in, const int* in_sizes, int n_in,
                              void* d_out, int out_size, void* d_ws, size_t ws_size,
                              hipStream_t stream) {
    const float* emb    = (const float*)d_in[0];
    const int*   labels = (const int*)d_in[1];   // harness passes integers as int32

    int N  = in_sizes[1];           // 16384
    int D  = in_sizes[0] / N;       // 128
    int D4 = D / 4;                 // 32

    float* out       = (float*)d_out;
    float* valid_out = out + (size_t)3 * N * D;  // tail of d_out: [N] valid mask

    int nblk = (N + WAVES_PER_BLOCK - 1) / WAVES_PER_BLOCK;
    triplet_fused_kernel<<<nblk, BLOCK, 0, stream>>>(
        labels, (const f32x4*)emb, (f32x4*)out, valid_out, N, D4);
}